// Round 6
// baseline (5294.324 us; speedup 1.0000x reference)
//
#include <hip/hip_runtime.h>

typedef unsigned short ushort_t;

__device__ __forceinline__ float bf2f(unsigned int u) {
    union { unsigned int i; float f; } c; c.i = u << 16; return c.f;
}
__device__ __forceinline__ unsigned int f2bf(float f) {
    union { float f; unsigned int i; } c; c.f = f;
    unsigned int x = c.i;
    unsigned int r = x + 0x7FFFu + ((x >> 16) & 1u);
    return r >> 16;  // RNE; finite inputs
}

// flag >= 0: index into dt[] (1 = fp32, 0 = bf16). flag == -1: force bf16. flag == -2: force fp32.
__device__ __forceinline__ bool is_f32(const int* dt, int flag) {
    return flag == -2 ? true : (flag == -1 ? false : (dt[flag] != 0));
}

__device__ __forceinline__ void load4(const void* p, size_t idx, bool f32,
                                      float& a0, float& a1, float& a2, float& a3) {
    if (f32) {
        float4 v = *(const float4*)((const float*)p + idx);
        a0 = v.x; a1 = v.y; a2 = v.z; a3 = v.w;
    } else {
        uint2 u = *(const uint2*)((const ushort_t*)p + idx);
        a0 = bf2f(u.x & 0xffff); a1 = bf2f(u.x >> 16);
        a2 = bf2f(u.y & 0xffff); a3 = bf2f(u.y >> 16);
    }
}
__device__ __forceinline__ float load1(const void* p, size_t idx, bool f32) {
    return f32 ? ((const float*)p)[idx] : bf2f((unsigned int)((const ushort_t*)p)[idx]);
}

// ---- per-tensor dtype detector. Block b handles tensor b. Honest bf16 normal/constant data
// never shows exp==0xFF or denormals; fp32 low-halves are ~uniform (random data) or exactly
// 0x0000 (constants like ones) -> two complementary tests. All-zero tensors classify as bf16,
// which is bounds-safe and value-correct for zeros under either true dtype. ----
struct DetectArgs { const void* p[15]; int n[15]; };

__global__ __launch_bounds__(256) void detect_kernel(DetectArgs a, int* dt) {
    int t = blockIdx.x;
    __shared__ int hitA, evenZero, oddNZ;
    if (threadIdx.x == 0) { hitA = 0; evenZero = 0; oddNZ = 0; }
    __syncthreads();
    if (t == 1) {  // rel_index: int64 iff second 32-bit word is 0 (values ~1983 otherwise)
        if (threadIdx.x == 0) dt[1] = (((const int*)a.p[1])[1] == 0) ? 1 : 0;
        return;
    }
    const ushort_t* w = (const ushort_t*)a.p[t];
    int S = a.n[t] < 4096 ? a.n[t] : 4096;  // <= element count: safe to read under both dtypes
    int la = 0, lez = 0, lon = 0;
    for (int i = threadIdx.x; i < S; i += 256) {
        unsigned int v = w[i];
        unsigned int e = (v >> 7) & 0xFFu;
        if (e == 0xFFu || (e == 0u && (v & 0x7Fu) != 0u)) la = 1;
        if ((i & 1) == 0) { if (v == 0u) lez++; }
        else             { if (v != 0u) lon++; }
    }
    if (la)  atomicOr(&hitA, 1);
    if (lez) atomicAdd(&evenZero, lez);
    if (lon) atomicAdd(&oddNZ, lon);
    __syncthreads();
    if (threadIdx.x == 0) {
        int P = S / 2;
        dt[t] = (hitA || (evenZero >= (P * 9) / 10 && oddNZ >= P / 2)) ? 1 : 0;
    }
}

// ---------------- LN stats: one wave per row of 512 ----------------
__global__ __launch_bounds__(64) void ln_stats_kernel(const void* __restrict__ xin, int xflag,
                                                      const int* __restrict__ dt,
                                                      float* __restrict__ mu,
                                                      float* __restrict__ rsig) {
    bool f32 = is_f32(dt, xflag);
    int row = blockIdx.x;
    int t = threadIdx.x;
    float v[8];
    load4(xin, (size_t)row * 512 + t * 8,     f32, v[0], v[1], v[2], v[3]);
    load4(xin, (size_t)row * 512 + t * 8 + 4, f32, v[4], v[5], v[6], v[7]);
    float s = 0.f, ss = 0.f;
#pragma unroll
    for (int i = 0; i < 8; ++i) { s += v[i]; ss += v[i] * v[i]; }
#pragma unroll
    for (int off = 32; off; off >>= 1) {
        s  += __shfl_down(s, off);
        ss += __shfl_down(ss, off);
    }
    if (t == 0) {
        float m = s * (1.0f / 512.0f);
        float var = ss * (1.0f / 512.0f) - m * m;
        mu[row] = m;
        rsig[row] = rsqrtf(var + 1e-5f);
    }
}

// ------------- GEMM, runtime dtypes via dt[] + per-operand flags. -------------
// C = act( op(A)[64-tile rows rowOffA+bm.., K] @ W[K, ldW] + bias ) (+ res).
// op(A) = LNA ? (A - mu[m])*rsig[m]*g[k] + b[k] : A.   COUT: 0 = bf16 C, 1 = fp32 C.
// 64x64 tile, BK=16, 256 threads, 4x4 per thread, fp32 accumulate.
template <bool LNA, int ACT, bool RESON, int COUT>
__global__ __launch_bounds__(256) void gemm_kernel(const void* __restrict__ A, int rowOffA, int lda, int aflag,
                                                   const int* __restrict__ dt,
                                                   const float* __restrict__ mu,
                                                   const float* __restrict__ rsig,
                                                   const void* __restrict__ lng, int gflag,
                                                   const void* __restrict__ lnb, int bbflag,
                                                   const void* __restrict__ W, int ldW, int wflag,
                                                   const void* __restrict__ bias, int biasflag,
                                                   const void* __restrict__ res, int rowOffR, int ldres, int rflag,
                                                   void* __restrict__ C, int rowOffC, int ldC,
                                                   int K) {
    bool af32 = is_f32(dt, aflag);
    bool wf32 = is_f32(dt, wflag);

    __shared__ float As[16][64];
    __shared__ float Bs[16][64];
    int tid = threadIdx.x;
    int bm = blockIdx.y * 64, bn = blockIdx.x * 64;
    int tx = tid & 15, ty = tid >> 4;
    int am = tid >> 2, ak = (tid & 3) * 4;
    int bk = tid >> 4, bn4 = (tid & 15) * 4;

    float mu_r = 0.f, rs_r = 1.f;
    if (LNA) { mu_r = mu[bm + am]; rs_r = rsig[bm + am]; }

    float acc[4][4] = {};
    for (int k0 = 0; k0 < K; k0 += 16) {
        float a0, a1, a2, a3;
        load4(A, (size_t)(rowOffA + bm + am) * lda + ak + k0, af32, a0, a1, a2, a3);
        if (LNA) {
            bool gf32 = is_f32(dt, gflag), bf32 = is_f32(dt, bbflag);
            float g0, g1, g2, g3, b0, b1, b2, b3;
            load4(lng, (size_t)(k0 + ak), gf32, g0, g1, g2, g3);
            load4(lnb, (size_t)(k0 + ak), bf32, b0, b1, b2, b3);
            a0 = (a0 - mu_r) * rs_r * g0 + b0;
            a1 = (a1 - mu_r) * rs_r * g1 + b1;
            a2 = (a2 - mu_r) * rs_r * g2 + b2;
            a3 = (a3 - mu_r) * rs_r * g3 + b3;
        }
        As[ak + 0][am] = a0;
        As[ak + 1][am] = a1;
        As[ak + 2][am] = a2;
        As[ak + 3][am] = a3;
        float w0, w1, w2, w3;
        load4(W, (size_t)(bk + k0) * ldW + bn + bn4, wf32, w0, w1, w2, w3);
        Bs[bk][bn4 + 0] = w0;
        Bs[bk][bn4 + 1] = w1;
        Bs[bk][bn4 + 2] = w2;
        Bs[bk][bn4 + 3] = w3;
        __syncthreads();
#pragma unroll
        for (int k = 0; k < 16; ++k) {
            float x0 = As[k][ty * 4 + 0], x1 = As[k][ty * 4 + 1];
            float x2 = As[k][ty * 4 + 2], x3 = As[k][ty * 4 + 3];
            float q0 = Bs[k][tx * 4 + 0], q1 = Bs[k][tx * 4 + 1];
            float q2 = Bs[k][tx * 4 + 2], q3 = Bs[k][tx * 4 + 3];
            acc[0][0] += x0 * q0; acc[0][1] += x0 * q1; acc[0][2] += x0 * q2; acc[0][3] += x0 * q3;
            acc[1][0] += x1 * q0; acc[1][1] += x1 * q1; acc[1][2] += x1 * q2; acc[1][3] += x1 * q3;
            acc[2][0] += x2 * q0; acc[2][1] += x2 * q1; acc[2][2] += x2 * q2; acc[2][3] += x2 * q3;
            acc[3][0] += x3 * q0; acc[3][1] += x3 * q1; acc[3][2] += x3 * q2; acc[3][3] += x3 * q3;
        }
        __syncthreads();
    }

    float bv[4] = {0.f, 0.f, 0.f, 0.f};
    if (bias) {
        bool bf32 = is_f32(dt, biasflag);
        load4(bias, (size_t)(bn + tx * 4), bf32, bv[0], bv[1], bv[2], bv[3]);
    }
    bool rf32 = RESON ? is_f32(dt, rflag) : false;
#pragma unroll
    for (int i = 0; i < 4; ++i) {
        int m = bm + ty * 4 + i;
        float o[4];
#pragma unroll
        for (int j = 0; j < 4; ++j) {
            float v = acc[i][j] + bv[j];
            if (ACT == 1) v = 0.5f * v * (1.0f + erff(v * 0.70710678118654752f));
            o[j] = v;
        }
        if (RESON) {
            float r0, r1, r2, r3;
            load4(res, (size_t)(rowOffR + m) * ldres + bn + tx * 4, rf32, r0, r1, r2, r3);
            o[0] += r0; o[1] += r1; o[2] += r2; o[3] += r3;
        }
        if (COUT == 0) {
            uint2 st;
            st.x = f2bf(o[0]) | (f2bf(o[1]) << 16);
            st.y = f2bf(o[2]) | (f2bf(o[3]) << 16);
            *(uint2*)((ushort_t*)C + (size_t)(rowOffC + m) * ldC + bn + tx * 4) = st;
        } else {
            *(float4*)((float*)C + (size_t)(rowOffC + m) * ldC + bn + tx * 4) =
                make_float4(o[0], o[1], o[2], o[3]);
        }
    }
}

// ---------------- Attention for ONE batch: one block per (l, h); in-place over Q cols ----------
// qkv: [1024, 1536] bf16 workspace. cols [0,512)=Q, [512,1024)=K, [1024,1536)=V, col = h*32+d.
__global__ __launch_bounds__(256) void attn_kernel(ushort_t* __restrict__ qkv,
                                                   const int* __restrict__ rel_index,
                                                   const void* __restrict__ bias_table,
                                                   const int* __restrict__ dt) {
    bool btf32 = dt[2] != 0;
    bool i64 = dt[1] != 0;
    int l = blockIdx.x, h = blockIdx.y;
    __shared__ float q_s[32];
    __shared__ float sc[1024];
    __shared__ float red[8];
    __shared__ float part[8][32];
    int tid = threadIdx.x;

    const float scale = 0.17677669529663687f;  // 1/sqrt(32)
    ushort_t* qrow = qkv + (size_t)l * 1536 + h * 32;
    if (tid < 32) q_s[tid] = bf2f((unsigned int)qrow[tid]) * scale;
    __syncthreads();

    const ushort_t* Kbase = qkv + 512 + h * 32;
    const int* ri = rel_index + (i64 ? (size_t)l * 2048 : (size_t)l * 1024);
    float lmax = -1e30f;
    for (int m = tid; m < 1024; m += 256) {
        const ushort_t* kr = Kbase + (size_t)m * 1536;
        float d = 0.f;
#pragma unroll
        for (int q8 = 0; q8 < 4; ++q8) {
            uint4 u = *(const uint4*)(kr + q8 * 8);
            d += q_s[q8 * 8 + 0] * bf2f(u.x & 0xffff) + q_s[q8 * 8 + 1] * bf2f(u.x >> 16)
               + q_s[q8 * 8 + 2] * bf2f(u.y & 0xffff) + q_s[q8 * 8 + 3] * bf2f(u.y >> 16)
               + q_s[q8 * 8 + 4] * bf2f(u.z & 0xffff) + q_s[q8 * 8 + 5] * bf2f(u.z >> 16)
               + q_s[q8 * 8 + 6] * bf2f(u.w & 0xffff) + q_s[q8 * 8 + 7] * bf2f(u.w >> 16);
        }
        int idx = i64 ? ri[2 * m] : ri[m];
        d += load1(bias_table, (size_t)idx * 16 + h, btf32);
        sc[m] = d;
        lmax = fmaxf(lmax, d);
    }
#pragma unroll
    for (int off = 32; off; off >>= 1) lmax = fmaxf(lmax, __shfl_down(lmax, off));
    if ((tid & 63) == 0) red[tid >> 6] = lmax;
    __syncthreads();
    float m4 = fmaxf(fmaxf(red[0], red[1]), fmaxf(red[2], red[3]));

    float lsum = 0.f;
    for (int m = tid; m < 1024; m += 256) {
        float e = __expf(sc[m] - m4);
        sc[m] = e;
        lsum += e;
    }
#pragma unroll
    for (int off = 32; off; off >>= 1) lsum += __shfl_down(lsum, off);
    if ((tid & 63) == 0) red[4 + (tid >> 6)] = lsum;
    __syncthreads();
    float rs = 1.0f / (red[4] + red[5] + red[6] + red[7]);

    int d = tid & 31, ch = tid >> 5;  // 8 chunks x 128 keys
    const ushort_t* Vbase = qkv + 1024 + h * 32 + d;
    float acc = 0.f;
    int m0 = ch * 128;
    for (int m = m0; m < m0 + 128; ++m)
        acc += sc[m] * bf2f((unsigned int)Vbase[(size_t)m * 1536]);
    part[ch][d] = acc;
    __syncthreads();
    if (tid < 32) {
        float o = 0.f;
#pragma unroll
        for (int c = 0; c < 8; ++c) o += part[c][tid];
        qrow[tid] = (ushort_t)f2bf(o * rs);
    }
}

extern "C" void kernel_launch(void* const* d_in, const int* in_sizes, int n_in,
                              void* d_out, int out_size, void* d_ws, size_t ws_size,
                              hipStream_t stream) {
    const void* x          = d_in[0];
    const int*  rel_index  = (const int*)d_in[1];
    const void* bias_table = d_in[2];
    const void* qkv_w      = d_in[3];
    const void* qkv_b      = d_in[4];
    const void* proj_w     = d_in[5];
    const void* proj_b     = d_in[6];
    const void* n1g        = d_in[7];
    const void* n1b        = d_in[8];
    const void* n2g        = d_in[9];
    const void* n2b        = d_in[10];
    const void* fc1_w      = d_in[11];
    const void* fc1_b      = d_in[12];
    const void* fc2_w      = d_in[13];
    const void* fc2_b      = d_in[14];
    float* out = (float*)d_out;  // reference's declared output dtype: float32

    // ws (3.27 MB): [0,3MiB) buf bf16; then fp32 mu1/rs1/mu2/rs2 [8192 each]; then int dt[16]
    ushort_t* buf = (ushort_t*)d_ws;
    float* mu1 = (float*)((char*)d_ws + (3u << 20));
    float* rs1 = mu1 + 8192;
    float* mu2 = rs1 + 8192;
    float* rs2 = mu2 + 8192;
    int* dt = (int*)(rs2 + 8192);

    DetectArgs da;
    for (int i = 0; i < 15; ++i) { da.p[i] = d_in[i]; da.n[i] = in_sizes[i]; }
    detect_kernel<<<15, 256, 0, stream>>>(da, dt);

    ln_stats_kernel<<<8192, 64, 0, stream>>>(x, 0, dt, mu1, rs1);

    for (int b = 0; b < 8; ++b) {
        int ro = b * 1024;
        // buf = LN1(x rows ro..) @ qkv_w + qkv_b   [1024 x 1536] bf16
        gemm_kernel<true, 0, false, 0><<<dim3(24, 16), 256, 0, stream>>>(
            x, ro, 512, 0, dt, mu1 + ro, rs1 + ro, n1g, 7, n1b, 8,
            qkv_w, 1536, 3, qkv_b, 4, nullptr, 0, 0, -1, buf, 0, 1536, 512);
        attn_kernel<<<dim3(1024, 16), 256, 0, stream>>>(buf, rel_index, bias_table, dt);
        // out rows ro.. = attnout @ proj_w + proj_b + x rows ro..   (fp32 out)
        gemm_kernel<false, 0, true, 1><<<dim3(8, 16), 256, 0, stream>>>(
            buf, 0, 1536, -1, dt, nullptr, nullptr, nullptr, 0, nullptr, 0,
            proj_w, 512, 5, proj_b, 6, x, ro, 512, 0, out, ro, 512, 512);
    }

    ln_stats_kernel<<<8192, 64, 0, stream>>>(out, -2, dt, mu2, rs2);

    for (int c = 0; c < 16; ++c) {
        int ro = c * 512;
        // buf = gelu(LN2(out rows ro..) @ fc1_w + fc1_b)   [512 x 2048] bf16
        gemm_kernel<true, 1, false, 0><<<dim3(32, 8), 256, 0, stream>>>(
            out, ro, 512, -2, dt, mu2 + ro, rs2 + ro, n2g, 9, n2b, 10,
            fc1_w, 2048, 11, fc1_b, 12, nullptr, 0, 0, -1, buf, 0, 2048, 512);
        // out rows ro.. = buf @ fc2_w + fc2_b + out rows ro..   (fp32, in-place safe per-thread)
        gemm_kernel<false, 0, true, 1><<<dim3(8, 8), 256, 0, stream>>>(
            buf, 0, 2048, -1, dt, nullptr, nullptr, nullptr, 0, nullptr, 0,
            fc2_w, 512, 13, fc2_b, 14, out, ro, 512, -2, out, ro, 512, 2048);
    }
}

// Round 7
// 1547.817 us; speedup vs baseline: 3.4205x; 3.4205x over previous
//
#include <hip/hip_runtime.h>

typedef unsigned short u16;
typedef __attribute__((ext_vector_type(8))) short bf16x8;   // 8 bf16 in 4 VGPRs
typedef __attribute__((ext_vector_type(4))) float f32x4;

__device__ __forceinline__ float bf2f(unsigned int u) {
    union { unsigned int i; float f; } c; c.i = u << 16; return c.f;
}
__device__ __forceinline__ unsigned int f2bf(float f) {
    union { float f; unsigned int i; } c; c.f = f;
    unsigned int x = c.i;
    unsigned int r = x + 0x7FFFu + ((x >> 16) & 1u);
    return r >> 16;  // RNE; finite inputs
}

// ---- weight convert+transpose: W fp32 [K][N] -> Wt bf16 [N][K], 32x32 LDS tiles ----
__global__ __launch_bounds__(256) void wconv_kernel(const float* __restrict__ W,
                                                    u16* __restrict__ Wt, int K, int N) {
    __shared__ u16 tile[32][36];
    int k0 = blockIdx.y * 32, n0 = blockIdx.x * 32;
    int t = threadIdx.x;
    int r = t >> 3, c4 = (t & 7) * 4;
    float4 v = *(const float4*)(W + (size_t)(k0 + r) * N + n0 + c4);
    tile[r][c4 + 0] = (u16)f2bf(v.x);
    tile[r][c4 + 1] = (u16)f2bf(v.y);
    tile[r][c4 + 2] = (u16)f2bf(v.z);
    tile[r][c4 + 3] = (u16)f2bf(v.w);
    __syncthreads();
    int n = t >> 3, k4 = (t & 7) * 4;
    u16 a0 = tile[k4 + 0][n], a1 = tile[k4 + 1][n];
    u16 a2 = tile[k4 + 2][n], a3 = tile[k4 + 3][n];
    uint2 st;
    st.x = (unsigned)a0 | ((unsigned)a1 << 16);
    st.y = (unsigned)a2 | ((unsigned)a3 << 16);
    *(uint2*)(Wt + (size_t)(n0 + n) * K + k0 + k4) = st;
}

// ---- LayerNorm fp32 in -> bf16 out. 256 threads = 4 waves, one row (512) per wave ----
__global__ __launch_bounds__(256) void ln_kernel(const float* __restrict__ x,
                                                 const float* __restrict__ g,
                                                 const float* __restrict__ b,
                                                 u16* __restrict__ y) {
    int row = blockIdx.x * 4 + (threadIdx.x >> 6);
    int t = threadIdx.x & 63;
    const float* xr = x + (size_t)row * 512 + t * 8;
    float4 a = *(const float4*)xr;
    float4 c = *(const float4*)(xr + 4);
    float v[8] = { a.x, a.y, a.z, a.w, c.x, c.y, c.z, c.w };
    float s = 0.f, ss = 0.f;
#pragma unroll
    for (int i = 0; i < 8; ++i) { s += v[i]; ss += v[i] * v[i]; }
#pragma unroll
    for (int off = 32; off; off >>= 1) {
        s  += __shfl_down(s, off);
        ss += __shfl_down(ss, off);
    }
    s = __shfl(s, 0); ss = __shfl(ss, 0);
    float mu = s * (1.0f / 512.0f);
    float var = ss * (1.0f / 512.0f) - mu * mu;
    float r = rsqrtf(var + 1e-5f);
    float4 g0 = *(const float4*)(g + t * 8);
    float4 g1 = *(const float4*)(g + t * 8 + 4);
    float4 b0 = *(const float4*)(b + t * 8);
    float4 b1 = *(const float4*)(b + t * 8 + 4);
    float gv[8] = { g0.x, g0.y, g0.z, g0.w, g1.x, g1.y, g1.z, g1.w };
    float bv[8] = { b0.x, b0.y, b0.z, b0.w, b1.x, b1.y, b1.z, b1.w };
    unsigned int o[4];
#pragma unroll
    for (int i = 0; i < 4; ++i) {
        float o0 = (v[2 * i] - mu) * r * gv[2 * i] + bv[2 * i];
        float o1 = (v[2 * i + 1] - mu) * r * gv[2 * i + 1] + bv[2 * i + 1];
        o[i] = f2bf(o0) | (f2bf(o1) << 16);
    }
    *(uint4*)(y + (size_t)row * 512 + t * 8) = make_uint4(o[0], o[1], o[2], o[3]);
}

// ---- MFMA GEMM: C[M,N] = act(A[M,K]bf16 @ Bt[N,K]bf16^T + bias fp32) (+res fp32) ----
// 128x128 tile, BK=32, 256 thr = 4 waves (2x2 of 64x64), 16x16x32 MFMA, fp32 acc.
// ACT: 1=exact GELU.  RES: 1=add res fp32.  COUT: 0=bf16 C, 1=fp32 C.
template <int ACT, int RES, int COUT>
__global__ __launch_bounds__(256) void gemm_mfma(const u16* __restrict__ A, int lda,
                                                 const u16* __restrict__ Bt,
                                                 const float* __restrict__ bias,
                                                 const float* __restrict__ res, int ldres,
                                                 void* __restrict__ C, int ldC, int K) {
    __shared__ u16 As[128 * 56];   // [row][k] stride 56 (112B, 16B-aligned)
    __shared__ u16 Bs[128 * 56];   // [col][k]
    int tid = threadIdx.x;
    int bm = blockIdx.y * 128, bn = blockIdx.x * 128;
    int lane = tid & 63, wv = tid >> 6;
    int q = lane >> 4, lr = lane & 15;
    int wr = wv >> 1, wc = wv & 1;
    int sr = tid >> 1, skh = (tid & 1) * 16;

    const u16* Ag = A + (size_t)(bm + sr) * lda + skh;
    const u16* Bg = Bt + (size_t)(bn + sr) * K + skh;
    u16* Asw = &As[sr * 56 + skh];
    u16* Bsw = &Bs[sr * 56 + skh];
    const u16* Apf = &As[(wr * 64 + lr) * 56 + q * 8];
    const u16* Bpf = &Bs[(wc * 64 + lr) * 56 + q * 8];

    f32x4 acc[4][4];
#pragma unroll
    for (int i = 0; i < 4; ++i)
#pragma unroll
        for (int j = 0; j < 4; ++j) acc[i][j] = (f32x4){0.f, 0.f, 0.f, 0.f};

    for (int k0 = 0; k0 < K; k0 += 32) {
        uint4 av0 = *(const uint4*)(Ag + k0);
        uint4 av1 = *(const uint4*)(Ag + k0 + 8);
        uint4 bv0 = *(const uint4*)(Bg + k0);
        uint4 bv1 = *(const uint4*)(Bg + k0 + 8);
        __syncthreads();
        *(uint4*)Asw = av0; *(uint4*)(Asw + 8) = av1;
        *(uint4*)Bsw = bv0; *(uint4*)(Bsw + 8) = bv1;
        __syncthreads();
        bf16x8 af[4], bfr[4];
#pragma unroll
        for (int i = 0; i < 4; ++i) af[i] = *(const bf16x8*)(Apf + i * 16 * 56);
#pragma unroll
        for (int j = 0; j < 4; ++j) bfr[j] = *(const bf16x8*)(Bpf + j * 16 * 56);
#pragma unroll
        for (int i = 0; i < 4; ++i)
#pragma unroll
            for (int j = 0; j < 4; ++j)
                acc[i][j] = __builtin_amdgcn_mfma_f32_16x16x32_bf16(af[i], bfr[j], acc[i][j], 0, 0, 0);
    }

    float bv[4];
#pragma unroll
    for (int j = 0; j < 4; ++j)
        bv[j] = bias ? bias[bn + wc * 64 + j * 16 + lr] : 0.f;
#pragma unroll
    for (int i = 0; i < 4; ++i) {
#pragma unroll
        for (int j = 0; j < 4; ++j) {
            int col = bn + wc * 64 + j * 16 + lr;
#pragma unroll
            for (int r = 0; r < 4; ++r) {
                int row = bm + wr * 64 + i * 16 + q * 4 + r;
                float v = acc[i][j][r] + bv[j];
                if (ACT) v = 0.5f * v * (1.0f + erff(v * 0.7071067811865475f));
                if (RES) v += res[(size_t)row * ldres + col];
                if (COUT == 0) ((u16*)C)[(size_t)row * ldC + col] = (u16)f2bf(v);
                else           ((float*)C)[(size_t)row * ldC + col] = v;
            }
        }
    }
}

// ---- K transpose: qkv-half [4096][1536] cols 512..1024 -> Kt[b][h][d][l] bf16 ----
__global__ __launch_bounds__(256) void ktrans_kernel(const u16* __restrict__ qkv,
                                                     u16* __restrict__ Kt) {
    __shared__ u16 tile[32][36];
    int lt = blockIdx.x, h = blockIdx.y, b = blockIdx.z;
    int t = threadIdx.x;
    int l = t >> 3, d4 = (t & 7) * 4;
    uint2 v = *(const uint2*)(qkv + ((size_t)(b * 1024 + lt * 32 + l)) * 1536 + 512 + h * 32 + d4);
    tile[l][d4 + 0] = (u16)(v.x & 0xffff);
    tile[l][d4 + 1] = (u16)(v.x >> 16);
    tile[l][d4 + 2] = (u16)(v.y & 0xffff);
    tile[l][d4 + 3] = (u16)(v.y >> 16);
    __syncthreads();
    int d = t >> 3, l4 = (t & 7) * 4;
    u16 a0 = tile[l4 + 0][d], a1 = tile[l4 + 1][d];
    u16 a2 = tile[l4 + 2][d], a3 = tile[l4 + 3][d];
    uint2 st;
    st.x = (unsigned)a0 | ((unsigned)a1 << 16);
    st.y = (unsigned)a2 | ((unsigned)a3 << 16);
    *(uint2*)(Kt + (((size_t)b * 16 + h) * 32 + d) * 1024 + lt * 32 + l4) = st;
}

// ---- Attention: block per (l, h, batch-in-half); coalesced K via Kt; in-place over Q ----
__global__ __launch_bounds__(256) void attn_kernel(u16* __restrict__ qkv,
                                                   const u16* __restrict__ Kt,
                                                   const int* __restrict__ rel_index,
                                                   const float* __restrict__ bias_table) {
    int l = blockIdx.x, h = blockIdx.y, z = blockIdx.z;
    __shared__ float q_s[32];
    __shared__ float sc[1024];
    __shared__ float red[8];
    __shared__ float part[8][32];
    int tid = threadIdx.x;

    u16* qkvz = qkv + (size_t)z * 1024 * 1536;
    u16* qrow = qkvz + (size_t)l * 1536 + h * 32;
    const float scale = 0.17677669529663687f;  // 1/sqrt(32)
    if (tid < 32) q_s[tid] = bf2f((unsigned)qrow[tid]) * scale;
    __syncthreads();

    const u16* Kb = Kt + ((size_t)z * 16 + h) * 32768;  // [32 d][1024 l]
    const int* ri = rel_index + (size_t)l * 1024;
    int m0 = tid * 4;
    float s0 = 0.f, s1 = 0.f, s2 = 0.f, s3 = 0.f;
#pragma unroll 8
    for (int d = 0; d < 32; ++d) {
        uint2 u = *(const uint2*)(Kb + d * 1024 + m0);
        float qd = q_s[d];
        s0 += qd * bf2f(u.x & 0xffff);
        s1 += qd * bf2f(u.x >> 16);
        s2 += qd * bf2f(u.y & 0xffff);
        s3 += qd * bf2f(u.y >> 16);
    }
    int4 riv = *(const int4*)(ri + m0);
    s0 += bias_table[(size_t)riv.x * 16 + h];
    s1 += bias_table[(size_t)riv.y * 16 + h];
    s2 += bias_table[(size_t)riv.z * 16 + h];
    s3 += bias_table[(size_t)riv.w * 16 + h];
    sc[m0 + 0] = s0; sc[m0 + 1] = s1; sc[m0 + 2] = s2; sc[m0 + 3] = s3;

    float lmax = fmaxf(fmaxf(s0, s1), fmaxf(s2, s3));
#pragma unroll
    for (int off = 32; off; off >>= 1) lmax = fmaxf(lmax, __shfl_down(lmax, off));
    if ((tid & 63) == 0) red[tid >> 6] = lmax;
    __syncthreads();
    float m4 = fmaxf(fmaxf(red[0], red[1]), fmaxf(red[2], red[3]));

    float lsum = 0.f;
    for (int m = tid; m < 1024; m += 256) {
        float e = __expf(sc[m] - m4);
        sc[m] = e;
        lsum += e;
    }
#pragma unroll
    for (int off = 32; off; off >>= 1) lsum += __shfl_down(lsum, off);
    if ((tid & 63) == 0) red[4 + (tid >> 6)] = lsum;
    __syncthreads();
    float rs = 1.0f / (red[4] + red[5] + red[6] + red[7]);

    int d = tid & 31, ch = tid >> 5;  // 8 chunks x 128 keys
    const u16* Vbase = qkvz + 1024 + h * 32 + d;
    float acc = 0.f;
    int mb = ch * 128;
    for (int m = mb; m < mb + 128; ++m)
        acc += sc[m] * bf2f((unsigned)Vbase[(size_t)m * 1536]);
    part[ch][d] = acc;
    __syncthreads();
    if (tid < 32) {
        float o = 0.f;
#pragma unroll
        for (int c = 0; c < 8; ++c) o += part[c][tid];
        qrow[tid] = (u16)f2bf(o * rs);
    }
}

extern "C" void kernel_launch(void* const* d_in, const int* in_sizes, int n_in,
                              void* d_out, int out_size, void* d_ws, size_t ws_size,
                              hipStream_t stream) {
    const float* x          = (const float*)d_in[0];
    const int*   rel_index  = (const int*)d_in[1];
    const float* bias_table = (const float*)d_in[2];
    const float* qkv_w      = (const float*)d_in[3];
    const float* qkv_b      = (const float*)d_in[4];
    const float* proj_w     = (const float*)d_in[5];
    const float* proj_b     = (const float*)d_in[6];
    const float* n1g        = (const float*)d_in[7];
    const float* n1b        = (const float*)d_in[8];
    const float* n2g        = (const float*)d_in[9];
    const float* n2b        = (const float*)d_in[10];
    const float* fc1_w      = (const float*)d_in[11];
    const float* fc1_b      = (const float*)d_in[12];
    const float* fc2_w      = (const float*)d_in[13];
    const float* fc2_b      = (const float*)d_in[14];
    float* out = (float*)d_out;

    // ws (30 MB, bf16 elems):
    //   wq_t[1536][512] @0 ; wp_t[512][512] @786432 ; w1_t[2048][512] @1048576 ;
    //   w2_t[512][2048] @2097152 ; h[8192][512] @3145728 ;
    //   big @7340032: qkvbuf[4096][1536] + Kt[4*16*32*1024] @13631488 ; hid reuses big.
    u16* ws16 = (u16*)d_ws;
    u16* wq_t = ws16;
    u16* wp_t = ws16 + 786432;
    u16* w1_t = ws16 + 1048576;
    u16* w2_t = ws16 + 2097152;
    u16* h    = ws16 + 3145728;
    u16* qkvb = ws16 + 7340032;
    u16* Kt   = ws16 + 13631488;
    u16* hid  = qkvb;

    // weight convert+transpose (fp32 [K][N] -> bf16 [N][K])
    wconv_kernel<<<dim3(48, 16), 256, 0, stream>>>(qkv_w, wq_t, 512, 1536);
    wconv_kernel<<<dim3(16, 16), 256, 0, stream>>>(proj_w, wp_t, 512, 512);
    wconv_kernel<<<dim3(64, 16), 256, 0, stream>>>(fc1_w, w1_t, 512, 2048);
    wconv_kernel<<<dim3(16, 64), 256, 0, stream>>>(fc2_w, w2_t, 2048, 512);

    // h = LN1(x)
    ln_kernel<<<2048, 256, 0, stream>>>(x, n1g, n1b, h);

    for (int half = 0; half < 2; ++half) {
        size_t ro = (size_t)half * 4096;
        // qkvbuf = h_half @ qkv_w + qkv_b   [4096 x 1536] bf16
        gemm_mfma<0, 0, 0><<<dim3(12, 32), 256, 0, stream>>>(
            h + ro * 512, 512, wq_t, qkv_b, nullptr, 0, qkvb, 1536, 512);
        // Kt = transpose of K columns
        ktrans_kernel<<<dim3(32, 16, 4), 256, 0, stream>>>(qkvb, Kt);
        // attention (softmax + rel-pos bias), in-place over Q cols
        attn_kernel<<<dim3(1024, 16, 4), 256, 0, stream>>>(qkvb, Kt, rel_index, bias_table);
        // out_half = attnout @ proj_w + proj_b + x_half   (fp32)
        gemm_mfma<0, 1, 1><<<dim3(4, 32), 256, 0, stream>>>(
            qkvb, 1536, wp_t, proj_b, x + ro * 512, 512, out + ro * 512, 512, 512);
    }

    // h = LN2(out)
    ln_kernel<<<2048, 256, 0, stream>>>(out, n2g, n2b, h);

    for (int half = 0; half < 2; ++half) {
        size_t ro = (size_t)half * 4096;
        // hid = gelu(h_half @ fc1_w + fc1_b)   [4096 x 2048] bf16
        gemm_mfma<1, 0, 0><<<dim3(16, 32), 256, 0, stream>>>(
            h + ro * 512, 512, w1_t, fc1_b, nullptr, 0, hid, 2048, 512);
        // out_half = hid @ fc2_w + fc2_b + out_half   (fp32, in-place)
        gemm_mfma<0, 1, 1><<<dim3(4, 32), 256, 0, stream>>>(
            hid, 2048, w2_t, fc2_b, out + ro * 512, 512, out + ro * 512, 512, 2048);
    }
}

// Round 8
// 471.681 us; speedup vs baseline: 11.2244x; 3.2815x over previous
//
#include <hip/hip_runtime.h>

typedef unsigned short u16;
typedef __attribute__((ext_vector_type(8))) short bf16x8;   // 8 bf16 in 4 VGPRs
typedef __attribute__((ext_vector_type(4))) float f32x4;

__device__ __forceinline__ float bf2f(unsigned int u) {
    union { unsigned int i; float f; } c; c.i = u << 16; return c.f;
}
__device__ __forceinline__ unsigned int f2bf(float f) {
    union { float f; unsigned int i; } c; c.f = f;
    unsigned int x = c.i;
    unsigned int r = x + 0x7FFFu + ((x >> 16) & 1u);
    return r >> 16;  // RNE; finite inputs
}

// ---- weight convert+transpose: W fp32 [K][N] -> Wt bf16 [N][K], 32x32 LDS tiles ----
__global__ __launch_bounds__(256) void wconv_kernel(const float* __restrict__ W,
                                                    u16* __restrict__ Wt, int K, int N) {
    __shared__ u16 tile[32][36];
    int k0 = blockIdx.y * 32, n0 = blockIdx.x * 32;
    int t = threadIdx.x;
    int r = t >> 3, c4 = (t & 7) * 4;
    float4 v = *(const float4*)(W + (size_t)(k0 + r) * N + n0 + c4);
    tile[r][c4 + 0] = (u16)f2bf(v.x);
    tile[r][c4 + 1] = (u16)f2bf(v.y);
    tile[r][c4 + 2] = (u16)f2bf(v.z);
    tile[r][c4 + 3] = (u16)f2bf(v.w);
    __syncthreads();
    int n = t >> 3, k4 = (t & 7) * 4;
    u16 a0 = tile[k4 + 0][n], a1 = tile[k4 + 1][n];
    u16 a2 = tile[k4 + 2][n], a3 = tile[k4 + 3][n];
    uint2 st;
    st.x = (unsigned)a0 | ((unsigned)a1 << 16);
    st.y = (unsigned)a2 | ((unsigned)a3 << 16);
    *(uint2*)(Wt + (size_t)(n0 + n) * K + k0 + k4) = st;
}

// ---- LayerNorm fp32 in -> bf16 out. 256 threads = 4 waves, one row (512) per wave ----
__global__ __launch_bounds__(256) void ln_kernel(const float* __restrict__ x,
                                                 const float* __restrict__ g,
                                                 const float* __restrict__ b,
                                                 u16* __restrict__ y) {
    int row = blockIdx.x * 4 + (threadIdx.x >> 6);
    int t = threadIdx.x & 63;
    const float* xr = x + (size_t)row * 512 + t * 8;
    float4 a = *(const float4*)xr;
    float4 c = *(const float4*)(xr + 4);
    float v[8] = { a.x, a.y, a.z, a.w, c.x, c.y, c.z, c.w };
    float s = 0.f, ss = 0.f;
#pragma unroll
    for (int i = 0; i < 8; ++i) { s += v[i]; ss += v[i] * v[i]; }
#pragma unroll
    for (int off = 32; off; off >>= 1) {
        s  += __shfl_down(s, off);
        ss += __shfl_down(ss, off);
    }
    s = __shfl(s, 0); ss = __shfl(ss, 0);
    float mu = s * (1.0f / 512.0f);
    float var = ss * (1.0f / 512.0f) - mu * mu;
    float r = rsqrtf(var + 1e-5f);
    float4 g0 = *(const float4*)(g + t * 8);
    float4 g1 = *(const float4*)(g + t * 8 + 4);
    float4 b0 = *(const float4*)(b + t * 8);
    float4 b1 = *(const float4*)(b + t * 8 + 4);
    float gv[8] = { g0.x, g0.y, g0.z, g0.w, g1.x, g1.y, g1.z, g1.w };
    float bv[8] = { b0.x, b0.y, b0.z, b0.w, b1.x, b1.y, b1.z, b1.w };
    unsigned int o[4];
#pragma unroll
    for (int i = 0; i < 4; ++i) {
        float o0 = (v[2 * i] - mu) * r * gv[2 * i] + bv[2 * i];
        float o1 = (v[2 * i + 1] - mu) * r * gv[2 * i + 1] + bv[2 * i + 1];
        o[i] = f2bf(o0) | (f2bf(o1) << 16);
    }
    *(uint4*)(y + (size_t)row * 512 + t * 8) = make_uint4(o[0], o[1], o[2], o[3]);
}

// ---- MFMA GEMM: C[M,N] = act(A[M,K]bf16 @ Bt[N,K]bf16^T + bias fp32) (+res fp32) ----
// 128x128 tile, BK=32, 256 thr = 4 waves (2x2 of 64x64), 16x16x32 MFMA, fp32 acc.
template <int ACT, int RES, int COUT>
__global__ __launch_bounds__(256) void gemm_mfma(const u16* __restrict__ A, int lda,
                                                 const u16* __restrict__ Bt,
                                                 const float* __restrict__ bias,
                                                 const float* __restrict__ res, int ldres,
                                                 void* __restrict__ C, int ldC, int K) {
    __shared__ u16 As[128 * 56];   // [row][k] stride 56 (112B, 16B-aligned)
    __shared__ u16 Bs[128 * 56];   // [col][k]
    int tid = threadIdx.x;
    int bm = blockIdx.y * 128, bn = blockIdx.x * 128;
    int lane = tid & 63, wv = tid >> 6;
    int q = lane >> 4, lr = lane & 15;
    int wr = wv >> 1, wc = wv & 1;
    int sr = tid >> 1, skh = (tid & 1) * 16;

    const u16* Ag = A + (size_t)(bm + sr) * lda + skh;
    const u16* Bg = Bt + (size_t)(bn + sr) * K + skh;
    u16* Asw = &As[sr * 56 + skh];
    u16* Bsw = &Bs[sr * 56 + skh];
    const u16* Apf = &As[(wr * 64 + lr) * 56 + q * 8];
    const u16* Bpf = &Bs[(wc * 64 + lr) * 56 + q * 8];

    f32x4 acc[4][4];
#pragma unroll
    for (int i = 0; i < 4; ++i)
#pragma unroll
        for (int j = 0; j < 4; ++j) acc[i][j] = (f32x4){0.f, 0.f, 0.f, 0.f};

    for (int k0 = 0; k0 < K; k0 += 32) {
        uint4 av0 = *(const uint4*)(Ag + k0);
        uint4 av1 = *(const uint4*)(Ag + k0 + 8);
        uint4 bv0 = *(const uint4*)(Bg + k0);
        uint4 bv1 = *(const uint4*)(Bg + k0 + 8);
        __syncthreads();
        *(uint4*)Asw = av0; *(uint4*)(Asw + 8) = av1;
        *(uint4*)Bsw = bv0; *(uint4*)(Bsw + 8) = bv1;
        __syncthreads();
        bf16x8 af[4], bfr[4];
#pragma unroll
        for (int i = 0; i < 4; ++i) af[i] = *(const bf16x8*)(Apf + i * 16 * 56);
#pragma unroll
        for (int j = 0; j < 4; ++j) bfr[j] = *(const bf16x8*)(Bpf + j * 16 * 56);
#pragma unroll
        for (int i = 0; i < 4; ++i)
#pragma unroll
            for (int j = 0; j < 4; ++j)
                acc[i][j] = __builtin_amdgcn_mfma_f32_16x16x32_bf16(af[i], bfr[j], acc[i][j], 0, 0, 0);
    }

    float bv[4];
#pragma unroll
    for (int j = 0; j < 4; ++j)
        bv[j] = bias ? bias[bn + wc * 64 + j * 16 + lr] : 0.f;
#pragma unroll
    for (int i = 0; i < 4; ++i) {
#pragma unroll
        for (int j = 0; j < 4; ++j) {
            int col = bn + wc * 64 + j * 16 + lr;
#pragma unroll
            for (int r = 0; r < 4; ++r) {
                int row = bm + wr * 64 + i * 16 + q * 4 + r;
                float v = acc[i][j][r] + bv[j];
                if (ACT) v = 0.5f * v * (1.0f + erff(v * 0.7071067811865475f));
                if (RES) v += res[(size_t)row * ldres + col];
                if (COUT == 0) ((u16*)C)[(size_t)row * ldC + col] = (u16)f2bf(v);
                else           ((float*)C)[(size_t)row * ldC + col] = v;
            }
        }
    }
}

// ---- Flash attention (MFMA): block = (qt 64 rows, head, batch-in-half). In-place over Q. ----
// qkv: [4096][1536] bf16. Q cols [0,512), K [512,1024), V [1024,1536); col = h*32+d.
__global__ __launch_bounds__(256) void attn_mfma(u16* __restrict__ qkv,
                                                 const int* __restrict__ rel_index,
                                                 const float* __restrict__ bias_table) {
    __shared__ u16 Ks[128][40];        // [key][d]  stride 80B (16B-aligned)
    __shared__ u16 Vt[32][136];        // [d][key]  stride 272B
    __shared__ u16 Ps[4][16][136];     // per-wave P stage [row][key]
    __shared__ float biasc[3969];      // bias_table column h
    int tid = threadIdx.x;
    int qt = blockIdx.x, h = blockIdx.y, z = blockIdx.z;
    u16* qkvz = qkv + (size_t)z * 1024 * 1536;

    for (int i = tid; i < 3969; i += 256) biasc[i] = bias_table[(size_t)i * 16 + h];

    int lane = tid & 63, wv = tid >> 6;
    int q = lane >> 4, m = lane & 15;

    // Q A-fragment (held for the whole block): rows qt*64 + wv*16 + m
    int qrow = qt * 64 + wv * 16 + m;
    bf16x8 qf = *(const bf16x8*)(qkvz + (size_t)qrow * 1536 + h * 32 + q * 8);

    const float scale = 0.17677669529663687f;  // 1/sqrt(32)
    float mrow[4] = { -1e30f, -1e30f, -1e30f, -1e30f };
    float lrow[4] = { 0.f, 0.f, 0.f, 0.f };
    f32x4 acco[2] = { (f32x4){0.f,0.f,0.f,0.f}, (f32x4){0.f,0.f,0.f,0.f} };

    for (int kt = 0; kt < 8; ++kt) {
        __syncthreads();
        {   // stage K row-major, V transposed; keys kt*128 ..+128
            int key = tid >> 1, dh = (tid & 1) * 16;
            const u16* ksrc = qkvz + (size_t)(kt * 128 + key) * 1536 + 512 + h * 32 + dh;
            uint4 k0 = *(const uint4*)ksrc;
            uint4 k1 = *(const uint4*)(ksrc + 8);
            *(uint4*)&Ks[key][dh] = k0;
            *(uint4*)&Ks[key][dh + 8] = k1;
            const u16* vsrc = qkvz + (size_t)(kt * 128 + key) * 1536 + 1024 + h * 32 + dh;
            uint4 v0 = *(const uint4*)vsrc;
            uint4 v1 = *(const uint4*)(vsrc + 8);
            u16 tmp[16];
            *(uint4*)tmp = v0; *(uint4*)(tmp + 8) = v1;
#pragma unroll
            for (int j = 0; j < 16; ++j) Vt[dh + j][key] = tmp[j];
        }
        __syncthreads();

        // QK: 8 sub-tiles of 16 keys, full hd=32 in one MFMA each
        f32x4 s8[8];
#pragma unroll
        for (int t = 0; t < 8; ++t) {
            bf16x8 kf = *(const bf16x8*)&Ks[t * 16 + m][q * 8];
            s8[t] = __builtin_amdgcn_mfma_f32_16x16x32_bf16(
                qf, kf, (f32x4){0.f,0.f,0.f,0.f}, 0, 0, 0);
        }
        // scale + rel-pos bias (C-layout: row q*4+r, col t*16+m)
#pragma unroll
        for (int t = 0; t < 8; ++t) {
            int key = kt * 128 + t * 16 + m;
#pragma unroll
            for (int r = 0; r < 4; ++r) {
                int l = qt * 64 + wv * 16 + q * 4 + r;
                int idx = rel_index[(size_t)l * 1024 + key];
                s8[t][r] = s8[t][r] * scale + biasc[idx];
            }
        }
        // online softmax
        float alpha[4];
#pragma unroll
        for (int r = 0; r < 4; ++r) {
            float v = s8[0][r];
#pragma unroll
            for (int t = 1; t < 8; ++t) v = fmaxf(v, s8[t][r]);
            v = fmaxf(v, __shfl_xor(v, 1));
            v = fmaxf(v, __shfl_xor(v, 2));
            v = fmaxf(v, __shfl_xor(v, 4));
            v = fmaxf(v, __shfl_xor(v, 8));
            float mn = fmaxf(mrow[r], v);
            alpha[r] = __expf(mrow[r] - mn);
            mrow[r] = mn;
            float sum = 0.f;
#pragma unroll
            for (int t = 0; t < 8; ++t) {
                float p = __expf(s8[t][r] - mn);
                s8[t][r] = p;
                sum += p;
            }
            sum += __shfl_xor(sum, 1);
            sum += __shfl_xor(sum, 2);
            sum += __shfl_xor(sum, 4);
            sum += __shfl_xor(sum, 8);
            lrow[r] = lrow[r] * alpha[r] + sum;
        }
        // P (bf16) -> wave-local LDS stage (C-layout rows)
#pragma unroll
        for (int t = 0; t < 8; ++t)
#pragma unroll
            for (int r = 0; r < 4; ++r)
                Ps[wv][q * 4 + r][t * 16 + m] = (u16)f2bf(s8[t][r]);
        __syncthreads();  // lgkmcnt(0): P visible to all lanes of the wave
        // rescale O accumulator
#pragma unroll
        for (int dt = 0; dt < 2; ++dt)
#pragma unroll
            for (int r = 0; r < 4; ++r) acco[dt][r] *= alpha[r];
        // PV: A = P (A-layout from LDS), B = V (via Vt), 4 K-chunks x 2 d-tiles
#pragma unroll
        for (int c = 0; c < 4; ++c) {
            bf16x8 pf = *(const bf16x8*)&Ps[wv][m][c * 32 + q * 8];
#pragma unroll
            for (int dt = 0; dt < 2; ++dt) {
                bf16x8 vf = *(const bf16x8*)&Vt[dt * 16 + m][c * 32 + q * 8];
                acco[dt] = __builtin_amdgcn_mfma_f32_16x16x32_bf16(pf, vf, acco[dt], 0, 0, 0);
            }
        }
    }
    // epilogue: O = acco / l -> overwrite Q cols of this block's rows
#pragma unroll
    for (int r = 0; r < 4; ++r) {
        int l = qt * 64 + wv * 16 + q * 4 + r;
        float inv = 1.0f / lrow[r];
#pragma unroll
        for (int dt = 0; dt < 2; ++dt)
            qkvz[(size_t)l * 1536 + h * 32 + dt * 16 + m] = (u16)f2bf(acco[dt][r] * inv);
    }
}

extern "C" void kernel_launch(void* const* d_in, const int* in_sizes, int n_in,
                              void* d_out, int out_size, void* d_ws, size_t ws_size,
                              hipStream_t stream) {
    const float* x          = (const float*)d_in[0];
    const int*   rel_index  = (const int*)d_in[1];
    const float* bias_table = (const float*)d_in[2];
    const float* qkv_w      = (const float*)d_in[3];
    const float* qkv_b      = (const float*)d_in[4];
    const float* proj_w     = (const float*)d_in[5];
    const float* proj_b     = (const float*)d_in[6];
    const float* n1g        = (const float*)d_in[7];
    const float* n1b        = (const float*)d_in[8];
    const float* n2g        = (const float*)d_in[9];
    const float* n2b        = (const float*)d_in[10];
    const float* fc1_w      = (const float*)d_in[11];
    const float* fc1_b      = (const float*)d_in[12];
    const float* fc2_w      = (const float*)d_in[13];
    const float* fc2_b      = (const float*)d_in[14];
    float* out = (float*)d_out;

    // ws (26 MB, bf16 elems): wq_t @0 ; wp_t @786432 ; w1_t @1048576 ; w2_t @2097152 ;
    //   h[8192][512] @3145728 ; qkvbuf[4096][1536] @7340032 (hid reuses it)
    u16* ws16 = (u16*)d_ws;
    u16* wq_t = ws16;
    u16* wp_t = ws16 + 786432;
    u16* w1_t = ws16 + 1048576;
    u16* w2_t = ws16 + 2097152;
    u16* h    = ws16 + 3145728;
    u16* qkvb = ws16 + 7340032;
    u16* hid  = qkvb;

    wconv_kernel<<<dim3(48, 16), 256, 0, stream>>>(qkv_w, wq_t, 512, 1536);
    wconv_kernel<<<dim3(16, 16), 256, 0, stream>>>(proj_w, wp_t, 512, 512);
    wconv_kernel<<<dim3(64, 16), 256, 0, stream>>>(fc1_w, w1_t, 512, 2048);
    wconv_kernel<<<dim3(16, 64), 256, 0, stream>>>(fc2_w, w2_t, 2048, 512);

    ln_kernel<<<2048, 256, 0, stream>>>(x, n1g, n1b, h);

    for (int half = 0; half < 2; ++half) {
        size_t ro = (size_t)half * 4096;
        gemm_mfma<0, 0, 0><<<dim3(12, 32), 256, 0, stream>>>(
            h + ro * 512, 512, wq_t, qkv_b, nullptr, 0, qkvb, 1536, 512);
        attn_mfma<<<dim3(16, 16, 4), 256, 0, stream>>>(qkvb, rel_index, bias_table);
        gemm_mfma<0, 1, 1><<<dim3(4, 32), 256, 0, stream>>>(
            qkvb, 1536, wp_t, proj_b, x + ro * 512, 512, out + ro * 512, 512, 512);
    }

    ln_kernel<<<2048, 256, 0, stream>>>(out, n2g, n2b, h);

    for (int half = 0; half < 2; ++half) {
        size_t ro = (size_t)half * 4096;
        gemm_mfma<1, 0, 0><<<dim3(16, 32), 256, 0, stream>>>(
            h + ro * 512, 512, w1_t, fc1_b, nullptr, 0, hid, 2048, 512);
        gemm_mfma<0, 1, 1><<<dim3(4, 32), 256, 0, stream>>>(
            hid, 2048, w2_t, fc2_b, out + ro * 512, 512, out + ro * 512, 512, 2048);
    }
}